// Round 8
// baseline (169.771 us; speedup 1.0000x reference)
//
#include <hip/hip_runtime.h>
#include <hip/hip_bf16.h>
#include <cstdint>
#include <cstddef>

#define SLEN 2048
#define DH   64
#define NHEADS 32        // B*H
#define LOG2E 1.44269504088896340736f

// Fragment-ordered KV pre-buffer: per head, per 64-key tile (16 KB):
//   K area (8 KB): chunk kci = t*2+c, lane l=(g,m):  K[64jt+16t+m][32c+8g+j]
//   V area (8 KB): chunk vci = kc*4+dt, lane l:      V[64jt+32kc+8g+j][16dt+m]
#define PRE_TILE 16384
#define PRE_HEAD (32 * PRE_TILE)                  // 512 KB per head
#define PRE_TOTAL ((size_t)NHEADS * PRE_HEAD)     // 16 MB

typedef short  bf16x8 __attribute__((ext_vector_type(8)));
typedef float  f32x4  __attribute__((ext_vector_type(4)));

__device__ __forceinline__ unsigned short f2bf(float f) {
    __hip_bfloat16 h = __float2bfloat16(f);
    return *reinterpret_cast<unsigned short*>(&h);
}
__device__ __forceinline__ unsigned int pk2(float a, float b) {
    return (unsigned int)f2bf(a) | ((unsigned int)f2bf(b) << 16);
}

// ---------------------------------------------------------------------------
// Prep: build the fragment-ordered bf16 KV buffer.
// Blocks 0..2047: K (1 thread per 16B output chunk, coalesced writes).
// Blocks 2048..3071: V (one 64x64 tile per block, transpose via LDS).
// ---------------------------------------------------------------------------
__global__ __launch_bounds__(256) void prep(const float* __restrict__ Kg,
                                            const float* __restrict__ Vg,
                                            unsigned short* __restrict__ ws)
{
    const int bid = blockIdx.x;
    const int tid = threadIdx.x;
    if (bid < 2048) {
        const int cid  = bid * 256 + tid;
        const int h    = cid >> 14;            // 16384 K-chunks per head
        const int rem  = cid & 16383;
        const int jt   = rem >> 9;             // 512 chunks per tile
        const int rem2 = rem & 511;
        const int kci  = rem2 >> 6;
        const int l    = rem2 & 63;
        const int t = kci >> 1, c = kci & 1, g = l >> 4, m = l & 15;
        const float* src =
            Kg + ((size_t)h * SLEN + 64 * jt + 16 * t + m) * DH + 32 * c + 8 * g;
        float4 a = *reinterpret_cast<const float4*>(src);
        float4 b = *reinterpret_cast<const float4*>(src + 4);
        bf16x8 o;
        o[0]=(short)f2bf(a.x); o[1]=(short)f2bf(a.y);
        o[2]=(short)f2bf(a.z); o[3]=(short)f2bf(a.w);
        o[4]=(short)f2bf(b.x); o[5]=(short)f2bf(b.y);
        o[6]=(short)f2bf(b.z); o[7]=(short)f2bf(b.w);
        *(bf16x8*)((char*)ws + (size_t)h * PRE_HEAD + (size_t)jt * PRE_TILE
                   + kci * 1024 + l * 16) = o;
    } else {
        __shared__ __attribute__((aligned(16))) unsigned short Vt[64 * 64];
        const int vb = bid - 2048;
        const int h  = vb >> 5;
        const int jt = vb & 31;
        // load: thread = (k-pair kp, d-octet do8); coalesced fp32 reads
        const int kp  = tid >> 3;
        const int do8 = tid & 7;
        const float* s0 =
            Vg + ((size_t)h * SLEN + 64 * jt + 2 * kp) * DH + 8 * do8;
        float4 a0 = *reinterpret_cast<const float4*>(s0);
        float4 a1 = *reinterpret_cast<const float4*>(s0 + 4);
        float4 b0 = *reinterpret_cast<const float4*>(s0 + DH);
        float4 b1 = *reinterpret_cast<const float4*>(s0 + DH + 4);
        float av[8] = {a0.x,a0.y,a0.z,a0.w,a1.x,a1.y,a1.z,a1.w};
        float bv[8] = {b0.x,b0.y,b0.z,b0.w,b1.x,b1.y,b1.z,b1.w};
        #pragma unroll
        for (int j = 0; j < 8; ++j) {
            const int d = 8 * do8 + j;
            // Vt logical [d][k] bf16; 16B-chunk swizzle: chunk ^= (d&7)
            const unsigned byte =
                (unsigned)(d * 128) + ((((unsigned)(kp >> 2)) ^ (unsigned)(d & 7)) << 4)
                + (unsigned)((kp & 3) * 4);
            *(unsigned*)((char*)Vt + byte) = pk2(av[j], bv[j]);
        }
        __syncthreads();
        // store: 2 fragment chunks per thread, coalesced 16B global writes
        char* base = (char*)ws + (size_t)h * PRE_HEAD + (size_t)jt * PRE_TILE + 8192;
        #pragma unroll
        for (int u = 0; u < 2; ++u) {
            const int cc  = 2 * tid + u;
            const int vci = cc >> 6;
            const int l   = cc & 63;
            const int kc = vci >> 2, dt = vci & 3, g = l >> 4, m = l & 15;
            const int d   = 16 * dt + m;
            const int kch = 4 * kc + g;
            bf16x8 v = *(const bf16x8*)((const char*)Vt + d * 128
                        + (((unsigned)kch ^ (unsigned)(d & 7)) << 4));
            *(bf16x8*)(base + vci * 1024 + l * 16) = v;
        }
    }
}

// ---------------------------------------------------------------------------
// Barrier-free attention: K/V fragments loaded straight to registers from the
// fragment-ordered pre-buffer (no LDS staging, no __syncthreads). One wave =
// 32 q-rows (2x16 halves sharing the K loads); P goes through per-wave LDS
// (same-wave DS is in-order). Block = 4 waves = 128 q-rows; grid 512 = 2
// independent waves/SIMD; XOR pairing (qtile, qtile^15) balances per-SIMD work.
// ---------------------------------------------------------------------------
__global__ __launch_bounds__(256, 2) void fattn_r(const float* __restrict__ Qg,
                                                  const unsigned short* __restrict__ KV,
                                                  float* __restrict__ Og)
{
    __shared__ __attribute__((aligned(16))) unsigned short Plds[4][2][16 * 64];

    const int bid   = blockIdx.x;
    const int hi    = bid >> 8;                     // 0/1 residency round
    const int qtile = (bid & 15) ^ (hi ? 15 : 0);   // balanced pairing
    const int head  = (bid >> 4) & 31;
    const int Qb    = qtile * 128;

    const float* Qp = Qg + (size_t)head * SLEN * DH;
    const char*  KH = (const char*)KV + (size_t)head * PRE_HEAD;
    float*       Op = Og + (size_t)head * SLEN * DH;

    const int tid  = threadIdx.x;
    const int w    = tid >> 6;
    const int lane = tid & 63;
    const int g    = lane >> 4;
    const int m    = lane & 15;

    char* P0 = (char*)&Plds[w][0][0];
    char* P1 = (char*)&Plds[w][1][0];
    const unsigned pswz = ((unsigned)(m & 7)) << 4;

    // ---- Q fragments: half h rows Qb+32w+16h+m, k = 32c+8g+j ----
    bf16x8 qf[2][2];
    {
        const float sc = 0.125f * LOG2E;
        #pragma unroll
        for (int h = 0; h < 2; ++h) {
            const int qrow = Qb + 32 * w + 16 * h + m;
            #pragma unroll
            for (int c = 0; c < 2; ++c) {
                const float* src = Qp + (size_t)qrow * DH + 32 * c + 8 * g;
                float4 a = *reinterpret_cast<const float4*>(src);
                float4 b = *reinterpret_cast<const float4*>(src + 4);
                bf16x8 qv;
                qv[0]=(short)f2bf(a.x*sc); qv[1]=(short)f2bf(a.y*sc);
                qv[2]=(short)f2bf(a.z*sc); qv[3]=(short)f2bf(a.w*sc);
                qv[4]=(short)f2bf(b.x*sc); qv[5]=(short)f2bf(b.y*sc);
                qv[6]=(short)f2bf(b.z*sc); qv[7]=(short)f2bf(b.w*sc);
                qf[h][c] = qv;
            }
        }
    }

    f32x4 o0[4], o1[4];
    #pragma unroll
    for (int dt = 0; dt < 4; ++dt) { o0[dt] = (f32x4){0,0,0,0}; o1[dt] = (f32x4){0,0,0,0}; }
    float mr0 = -1e30f, lr0 = 0.f, mr1 = -1e30f, lr1 = 0.f;

    const int q0 = Qb + 32 * w + m;
    const int q1 = q0 + 16;
    const int nt = 2 * qtile + 1 + (w >> 1);   // per-wave causal tile count

    const char* tb = KH;
    for (int jt = 0; jt < nt; ++jt, tb += PRE_TILE) {
        const bool last = (jt == nt - 1);
        const int  kvb  = jt * 64;

        // ---- K fragments -> regs (8 x dwordx4, coalesced, L2-resident) ----
        bf16x8 kf[8];
        #pragma unroll
        for (int i = 0; i < 8; ++i)
            kf[i] = *(const bf16x8*)(tb + i * 1024 + lane * 16);

        // ---- QK^T swapped, both halves: s[t] rows k=16t+4g+r, col q=m ----
        f32x4 s0[4], s1[4];
        #pragma unroll
        for (int t = 0; t < 4; ++t) { s0[t] = (f32x4){0,0,0,0}; s1[t] = (f32x4){0,0,0,0}; }
        #pragma unroll
        for (int c = 0; c < 2; ++c) {
            #pragma unroll
            for (int t = 0; t < 4; ++t)
                s0[t] = __builtin_amdgcn_mfma_f32_16x16x32_bf16(kf[2*t+c], qf[0][c], s0[t], 0, 0, 0);
            #pragma unroll
            for (int t = 0; t < 4; ++t)
                s1[t] = __builtin_amdgcn_mfma_f32_16x16x32_bf16(kf[2*t+c], qf[1][c], s1[t], 0, 0, 0);
        }

        // ---- V fragments -> regs (latency covered by softmax below) ----
        bf16x8 vf[8];
        #pragma unroll
        for (int i = 0; i < 8; ++i)
            vf[i] = *(const bf16x8*)(tb + 8192 + i * 1024 + lane * 16);

        // ---- softmax halves (row q lane-local; 2 butterflies over g) ----
        #pragma unroll
        for (int h = 0; h < 2; ++h) {
            f32x4* s   = h ? s1 : s0;
            float& mr  = h ? mr1 : mr0;
            float& lr  = h ? lr1 : lr0;
            f32x4* o   = h ? o1 : o0;
            const int q = h ? q1 : q0;
            char*  Pb  = h ? P1 : P0;

            float mx = -1e30f;
            #pragma unroll
            for (int t = 0; t < 4; ++t) {
                #pragma unroll
                for (int r = 0; r < 4; ++r) {
                    float v = s[t][r];
                    if (last) {
                        const int kk = kvb + 16 * t + 4 * g + r;
                        v = (kk > q) ? -1e30f : v;
                    }
                    s[t][r] = v;
                    mx = fmaxf(mx, v);
                }
            }
            mx = fmaxf(mx, __shfl_xor(mx, 16));
            mx = fmaxf(mx, __shfl_xor(mx, 32));

            if (__any(mx > mr)) {        // defer-rescale (THR=0, exact)
                const float mnew = fmaxf(mr, mx);
                const float fs   = exp2f(mr - mnew);
                mr = mnew;
                lr *= fs;
                float fso[4];
                #pragma unroll
                for (int r = 0; r < 4; ++r)
                    fso[r] = __shfl(fs, (lane & 48) | (4 * g + r));
                #pragma unroll
                for (int dt = 0; dt < 4; ++dt) {
                    #pragma unroll
                    for (int r = 0; r < 4; ++r) o[dt][r] *= fso[r];
                }
            }

            float ps = 0.f;
            #pragma unroll
            for (int t = 0; t < 4; ++t) {
                const float p0 = exp2f(s[t][0] - mr);
                const float p1 = exp2f(s[t][1] - mr);
                const float p2 = exp2f(s[t][2] - mr);
                const float p3 = exp2f(s[t][3] - mr);
                ps += (p0 + p1) + (p2 + p3);
                uint2 e;
                e.x = pk2(p0, p1);
                e.y = pk2(p2, p3);
                const unsigned byte = (unsigned)(m * 128 + 32 * t + 8 * g);
                *(uint2*)(Pb + (byte ^ pswz)) = e;   // same-wave DS: in-order
            }
            ps += __shfl_xor(ps, 16);
            ps += __shfl_xor(ps, 32);
            lr += ps;
        }

        // ---- PV both halves from register V-fragments ----
        #pragma unroll
        for (int kc = 0; kc < 2; ++kc) {
            const unsigned ab = ((unsigned)(m * 128 + 64 * kc + 16 * g)) ^ pswz;
            bf16x8 pa0 = *(const bf16x8*)(P0 + ab);
            bf16x8 pa1 = *(const bf16x8*)(P1 + ab);
            #pragma unroll
            for (int dt = 0; dt < 4; ++dt) {
                o0[dt] = __builtin_amdgcn_mfma_f32_16x16x32_bf16(pa0, vf[kc*4+dt], o0[dt], 0, 0, 0);
                o1[dt] = __builtin_amdgcn_mfma_f32_16x16x32_bf16(pa1, vf[kc*4+dt], o1[dt], 0, 0, 0);
            }
        }
    }

    // ---- epilogue ----
    #pragma unroll
    for (int h = 0; h < 2; ++h) {
        const float invl = 1.0f / (h ? lr1 : lr0);
        f32x4* o = h ? o1 : o0;
        float invo[4];
        #pragma unroll
        for (int r = 0; r < 4; ++r)
            invo[r] = __shfl(invl, (lane & 48) | (4 * g + r));
        #pragma unroll
        for (int r = 0; r < 4; ++r) {
            const int qrow = Qb + 32 * w + 16 * h + 4 * g + r;
            float* dst = Op + (size_t)qrow * DH;
            #pragma unroll
            for (int dt = 0; dt < 4; ++dt) dst[16 * dt + m] = o[dt][r] * invo[r];
        }
    }
}

// ---------------------------------------------------------------------------
// Fallback (validated round-4 kernel) if ws too small.
// ---------------------------------------------------------------------------
__global__ __launch_bounds__(256, 4) void fattn_s(const float* __restrict__ Qg,
                                                  const float* __restrict__ Kg,
                                                  const float* __restrict__ Vg,
                                                  float* __restrict__ Og)
{
    __shared__ __attribute__((aligned(16))) unsigned short Klds[128 * DH];
    __shared__ __attribute__((aligned(16))) unsigned short Vlds[DH * 128];
    __shared__ __attribute__((aligned(16))) unsigned short Plds[4][16 * 128];

    const int bid = blockIdx.x;
    const int hi4 = bid >> 8;
    const int lo8 = bid & 255;
    const int qx  = (int)((0x0F101F00u >> (8 * hi4)) & 31u);
    const int qt  = (lo8 & 31) ^ qx;
    const int bh  = (hi4 << 3) | (lo8 >> 5);
    const int qb  = qt * 64;

    const float* Qp = Qg + (size_t)bh * SLEN * DH;
    const float* Kp = Kg + (size_t)bh * SLEN * DH;
    const float* Vp = Vg + (size_t)bh * SLEN * DH;
    float*       Op = Og + (size_t)bh * SLEN * DH;

    const int tid  = threadIdx.x;
    const int w    = tid >> 6;
    const int lane = tid & 63;
    const int g    = lane >> 4;
    const int m    = lane & 15;

    bf16x8 qf[2];
    {
        const float sc = 0.125f * LOG2E;
        const int qrow = qb + 16 * w + m;
        #pragma unroll
        for (int c = 0; c < 2; ++c) {
            const float* src = Qp + (size_t)qrow * DH + 32 * c + 8 * g;
            float4 a = *reinterpret_cast<const float4*>(src);
            float4 b = *reinterpret_cast<const float4*>(src + 4);
            bf16x8 qv;
            qv[0]=(short)f2bf(a.x*sc); qv[1]=(short)f2bf(a.y*sc);
            qv[2]=(short)f2bf(a.z*sc); qv[3]=(short)f2bf(a.w*sc);
            qv[4]=(short)f2bf(b.x*sc); qv[5]=(short)f2bf(b.y*sc);
            qv[6]=(short)f2bf(b.z*sc); qv[7]=(short)f2bf(b.w*sc);
            qf[c] = qv;
        }
    }

    f32x4 o[4];
    #pragma unroll
    for (int dt = 0; dt < 4; ++dt) o[dt] = (f32x4){0.f, 0.f, 0.f, 0.f};
    float mrun = -1e30f, lrun = 0.f;

    const int klim = qb + 64;
    const int nt   = (qt + 2) >> 1;

    const int rk = tid & 127, hk = tid >> 7;
    const int kp = tid & 63,  dq = tid >> 6;

    char* Pw = (char*)&Plds[w][0];
    const unsigned pswz = ((unsigned)(m & 7)) << 4;
    const int q = qb + 16 * w + m;

    for (int jt = 0; jt < nt; ++jt) {
        const int kvb    = jt * 128;
        const int kwidth = min(128, klim - kvb);
        const bool last  = (jt == nt - 1);

        if (rk < kwidth) {
            const float4* s4 = reinterpret_cast<const float4*>(
                Kp + (size_t)(kvb + rk) * DH + 32 * hk);
            float4 x[8];
            #pragma unroll
            for (int i = 0; i < 8; ++i) x[i] = s4[i];
            const unsigned rswz = ((unsigned)(rk & 7)) << 4;
            #pragma unroll
            for (int c = 0; c < 4; ++c) {
                bf16x8 kb;
                kb[0]=(short)f2bf(x[2*c].x);   kb[1]=(short)f2bf(x[2*c].y);
                kb[2]=(short)f2bf(x[2*c].z);   kb[3]=(short)f2bf(x[2*c].w);
                kb[4]=(short)f2bf(x[2*c+1].x); kb[5]=(short)f2bf(x[2*c+1].y);
                kb[6]=(short)f2bf(x[2*c+1].z); kb[7]=(short)f2bf(x[2*c+1].w);
                const unsigned byte = (unsigned)(rk * 128 + 64 * hk + 16 * c);
                *(bf16x8*)((char*)Klds + (byte ^ rswz)) = kb;
            }
        }
        if (2 * kp < kwidth) {
            const float* s0 = Vp + (size_t)(kvb + 2 * kp) * DH + 16 * dq;
            float av[16], bv[16];
            #pragma unroll
            for (int i = 0; i < 4; ++i) {
                float4 ta = *reinterpret_cast<const float4*>(s0 + 4 * i);
                float4 tb = *reinterpret_cast<const float4*>(s0 + DH + 4 * i);
                av[4*i]=ta.x; av[4*i+1]=ta.y; av[4*i+2]=ta.z; av[4*i+3]=ta.w;
                bv[4*i]=tb.x; bv[4*i+1]=tb.y; bv[4*i+2]=tb.z; bv[4*i+3]=tb.w;
            }
            #pragma unroll
            for (int j = 0; j < 16; ++j) {
                const int d = 16 * dq + j;
                const unsigned byte = (unsigned)(d * 256 + 4 * kp);
                *(unsigned*)((char*)Vlds + (byte ^ (((unsigned)(d & 7)) << 4))) =
                    pk2(av[j], bv[j]);
            }
        }
        __syncthreads();

        f32x4 s[8];
        #pragma unroll
        for (int t = 0; t < 8; ++t) {
            if (16 * t < kwidth) {
                s[t] = (f32x4){0.f, 0.f, 0.f, 0.f};
                #pragma unroll
                for (int c = 0; c < 2; ++c) {
                    const unsigned row  = (unsigned)(16 * t + m);
                    const unsigned byte =
                        (row * 128u + (unsigned)(32 * c + 8 * g) * 2u) ^ ((row & 7u) << 4);
                    bf16x8 kf = *(const bf16x8*)((const char*)Klds + byte);
                    s[t] = __builtin_amdgcn_mfma_f32_16x16x32_bf16(kf, qf[c], s[t], 0, 0, 0);
                }
            }
        }

        float mx = -1e30f;
        #pragma unroll
        for (int t = 0; t < 8; ++t) {
            if (16 * t < kwidth) {
                #pragma unroll
                for (int r = 0; r < 4; ++r) {
                    float v = s[t][r];
                    if (last) {
                        const int kk = kvb + 16 * t + 4 * g + r;
                        v = (kk > q) ? -1e30f : v;
                    }
                    s[t][r] = v;
                    mx = fmaxf(mx, v);
                }
            }
        }
        mx = fmaxf(mx, __shfl_xor(mx, 16));
        mx = fmaxf(mx, __shfl_xor(mx, 32));
        const float mnew = fmaxf(mrun, mx);
        const float fs   = exp2f(mrun - mnew);
        mrun = mnew;

        float psum = 0.f;
        #pragma unroll
        for (int t = 0; t < 8; ++t) {
            if (16 * t < kwidth) {
                const float p0 = exp2f(s[t][0] - mnew);
                const float p1 = exp2f(s[t][1] - mnew);
                const float p2 = exp2f(s[t][2] - mnew);
                const float p3 = exp2f(s[t][3] - mnew);
                psum += (p0 + p1) + (p2 + p3);
                uint2 e;
                e.x = pk2(p0, p1);
                e.y = pk2(p2, p3);
                const unsigned byte = (unsigned)(m * 256 + 32 * t + 8 * g);
                *(uint2*)(Pw + (byte ^ pswz)) = e;
            }
        }
        psum += __shfl_xor(psum, 16);
        psum += __shfl_xor(psum, 32);
        lrun = lrun * fs + psum;

        float fso[4];
        #pragma unroll
        for (int r = 0; r < 4; ++r)
            fso[r] = __shfl(fs, (lane & 48) | (4 * g + r));
        #pragma unroll
        for (int dt = 0; dt < 4; ++dt) {
            #pragma unroll
            for (int r = 0; r < 4; ++r) o[dt][r] *= fso[r];
        }

        const int kclim = kwidth >> 5;
        #pragma unroll
        for (int kc = 0; kc < 4; ++kc) {
            if (kc < kclim) {
                const unsigned ab = ((unsigned)(m * 256 + 64 * kc + 16 * g)) ^ pswz;
                bf16x8 pa = *(const bf16x8*)(Pw + ab);
                #pragma unroll
                for (int dt = 0; dt < 4; ++dt) {
                    const unsigned d  = (unsigned)(16 * dt + m);
                    const unsigned vby =
                        (d * 256u + (unsigned)(64 * kc + 16 * g)) ^ ((d & 7u) << 4);
                    bf16x8 vfb = *(const bf16x8*)((const char*)Vlds + vby);
                    o[dt] = __builtin_amdgcn_mfma_f32_16x16x32_bf16(pa, vfb, o[dt], 0, 0, 0);
                }
            }
        }
        __syncthreads();
    }

    const float invl = 1.0f / lrun;
    float invo[4];
    #pragma unroll
    for (int r = 0; r < 4; ++r)
        invo[r] = __shfl(invl, (lane & 48) | (4 * g + r));
    #pragma unroll
    for (int r = 0; r < 4; ++r) {
        const int qrow = qb + 16 * w + 4 * g + r;
        float* dst = Op + (size_t)qrow * DH;
        #pragma unroll
        for (int dt = 0; dt < 4; ++dt) dst[16 * dt + m] = o[dt][r] * invo[r];
    }
}

extern "C" void kernel_launch(void* const* d_in, const int* in_sizes, int n_in,
                              void* d_out, int out_size, void* d_ws, size_t ws_size,
                              hipStream_t stream) {
    const float* Q = (const float*)d_in[0];
    const float* K = (const float*)d_in[1];
    const float* V = (const float*)d_in[2];
    float* O = (float*)d_out;
    if (ws_size >= PRE_TOTAL) {
        unsigned short* ws = (unsigned short*)d_ws;
        prep<<<dim3(3072), dim3(256), 0, stream>>>(K, V, ws);
        fattn_r<<<dim3(512), dim3(256), 0, stream>>>(Q, ws, O);
    } else {
        fattn_s<<<dim3(1024), dim3(256), 0, stream>>>(Q, K, V, O);
    }
}

// Round 9
// 150.787 us; speedup vs baseline: 1.1259x; 1.1259x over previous
//
#include <hip/hip_runtime.h>
#include <hip/hip_bf16.h>
#include <cstdint>
#include <cstddef>

#define SLEN 2048
#define DH   64
#define NHEADS 32        // B*H
#define LOG2E 1.44269504088896340736f

// Fragment-ordered KV pre-buffer: per head, per 64-key tile (16 KB):
//   K area (8 KB): chunk kci = t*2+c, lane l=(g,m):  K[64jt+16t+m][32c+8g+j]
//   V area (8 KB): chunk vci = kc*4+dt, lane l:      V[64jt+32kc+8g+j][16dt+m]
#define PRE_TILE 16384
#define PRE_HEAD (32 * PRE_TILE)                  // 512 KB per head
#define PRE_TOTAL ((size_t)NHEADS * PRE_HEAD)     // 16 MB

typedef short  bf16x8 __attribute__((ext_vector_type(8)));
typedef float  f32x4  __attribute__((ext_vector_type(4)));

__device__ __forceinline__ unsigned short f2bf(float f) {
    __hip_bfloat16 h = __float2bfloat16(f);
    return *reinterpret_cast<unsigned short*>(&h);
}
__device__ __forceinline__ unsigned int pk2(float a, float b) {
    return (unsigned int)f2bf(a) | ((unsigned int)f2bf(b) << 16);
}

// ---------------------------------------------------------------------------
// Prep (validated round 8): build the fragment-ordered bf16 KV buffer.
// Blocks 0..2047: K (1 thread per 16B output chunk, coalesced).
// Blocks 2048..3071: V (one 64x64 tile per block, transpose via LDS).
// ---------------------------------------------------------------------------
__global__ __launch_bounds__(256) void prep(const float* __restrict__ Kg,
                                            const float* __restrict__ Vg,
                                            unsigned short* __restrict__ ws)
{
    const int bid = blockIdx.x;
    const int tid = threadIdx.x;
    if (bid < 2048) {
        const int cid  = bid * 256 + tid;
        const int h    = cid >> 14;            // 16384 K-chunks per head
        const int rem  = cid & 16383;
        const int jt   = rem >> 9;             // 512 chunks per tile
        const int rem2 = rem & 511;
        const int kci  = rem2 >> 6;
        const int l    = rem2 & 63;
        const int t = kci >> 1, c = kci & 1, g = l >> 4, m = l & 15;
        const float* src =
            Kg + ((size_t)h * SLEN + 64 * jt + 16 * t + m) * DH + 32 * c + 8 * g;
        float4 a = *reinterpret_cast<const float4*>(src);
        float4 b = *reinterpret_cast<const float4*>(src + 4);
        bf16x8 o;
        o[0]=(short)f2bf(a.x); o[1]=(short)f2bf(a.y);
        o[2]=(short)f2bf(a.z); o[3]=(short)f2bf(a.w);
        o[4]=(short)f2bf(b.x); o[5]=(short)f2bf(b.y);
        o[6]=(short)f2bf(b.z); o[7]=(short)f2bf(b.w);
        *(bf16x8*)((char*)ws + (size_t)h * PRE_HEAD + (size_t)jt * PRE_TILE
                   + kci * 1024 + l * 16) = o;
    } else {
        __shared__ __attribute__((aligned(16))) unsigned short Vt[64 * 64];
        const int vb = bid - 2048;
        const int h  = vb >> 5;
        const int jt = vb & 31;
        const int kp  = tid >> 3;
        const int do8 = tid & 7;
        const float* s0 =
            Vg + ((size_t)h * SLEN + 64 * jt + 2 * kp) * DH + 8 * do8;
        float4 a0 = *reinterpret_cast<const float4*>(s0);
        float4 a1 = *reinterpret_cast<const float4*>(s0 + 4);
        float4 b0 = *reinterpret_cast<const float4*>(s0 + DH);
        float4 b1 = *reinterpret_cast<const float4*>(s0 + DH + 4);
        float av[8] = {a0.x,a0.y,a0.z,a0.w,a1.x,a1.y,a1.z,a1.w};
        float bv[8] = {b0.x,b0.y,b0.z,b0.w,b1.x,b1.y,b1.z,b1.w};
        #pragma unroll
        for (int j = 0; j < 8; ++j) {
            const int d = 8 * do8 + j;
            const unsigned byte =
                (unsigned)(d * 128) + ((((unsigned)(kp >> 2)) ^ (unsigned)(d & 7)) << 4)
                + (unsigned)((kp & 3) * 4);
            *(unsigned*)((char*)Vt + byte) = pk2(av[j], bv[j]);
        }
        __syncthreads();
        char* base = (char*)ws + (size_t)h * PRE_HEAD + (size_t)jt * PRE_TILE + 8192;
        #pragma unroll
        for (int u = 0; u < 2; ++u) {
            const int cc  = 2 * tid + u;
            const int vci = cc >> 6;
            const int l   = cc & 63;
            const int kc = vci >> 2, dt = vci & 3, g = l >> 4, m = l & 15;
            const int d   = 16 * dt + m;
            const int kch = 4 * kc + g;
            bf16x8 v = *(const bf16x8*)((const char*)Vt + d * 128
                        + (((unsigned)kch ^ (unsigned)(d & 7)) << 4));
            *(bf16x8*)(base + vci * 1024 + l * 16) = v;
        }
    }
}

// ---------------------------------------------------------------------------
// Barrier-free attention, high-occupancy form: wave = 16 q-rows -> 4096 waves
// total -> 4 waves/SIMD (grid 1024 x 4-wave blocks, 4 blocks/CU). Each wave
// loads K/V fragments straight to registers; the 4 waves of a block walk the
// same 16 KB tile (L1-served redundancy). No __syncthreads anywhere. P goes
// through per-wave LDS (same-wave DS is in-order). XOR-balanced residency:
// co-resident qt sets {q, q^31, q^16, q^15} sum to a constant 66 tiles.
// ---------------------------------------------------------------------------
__global__ __launch_bounds__(256, 4) void fattn_w(const float* __restrict__ Qg,
                                                  const unsigned short* __restrict__ KV,
                                                  float* __restrict__ Og)
{
    __shared__ __attribute__((aligned(16))) unsigned short Plds[4][16 * 64];

    const int bid = blockIdx.x;
    const int hi4 = bid >> 8;          // 0..3
    const int lo8 = bid & 255;
    const int qx  = (int)((0x0F101F00u >> (8 * hi4)) & 31u);  // {0,31,16,15}
    const int qt  = (lo8 & 31) ^ qx;
    const int head = (hi4 << 3) | (lo8 >> 5);
    const int qb  = qt * 64;

    const float* Qp = Qg + (size_t)head * SLEN * DH;
    const char*  KH = (const char*)KV + (size_t)head * PRE_HEAD;
    float*       Op = Og + (size_t)head * SLEN * DH;

    const int tid  = threadIdx.x;
    const int w    = tid >> 6;
    const int lane = tid & 63;
    const int g    = lane >> 4;
    const int m    = lane & 15;

    char* Pw = (char*)&Plds[w][0];
    const unsigned pswz = ((unsigned)(m & 7)) << 4;

    // ---- Q fragments: rows qb+16w+m, k = 32c+8g+j ----
    bf16x8 qf[2];
    {
        const float sc = 0.125f * LOG2E;
        const int qrow = qb + 16 * w + m;
        #pragma unroll
        for (int c = 0; c < 2; ++c) {
            const float* src = Qp + (size_t)qrow * DH + 32 * c + 8 * g;
            float4 a = *reinterpret_cast<const float4*>(src);
            float4 b = *reinterpret_cast<const float4*>(src + 4);
            bf16x8 qv;
            qv[0]=(short)f2bf(a.x*sc); qv[1]=(short)f2bf(a.y*sc);
            qv[2]=(short)f2bf(a.z*sc); qv[3]=(short)f2bf(a.w*sc);
            qv[4]=(short)f2bf(b.x*sc); qv[5]=(short)f2bf(b.y*sc);
            qv[6]=(short)f2bf(b.z*sc); qv[7]=(short)f2bf(b.w*sc);
            qf[c] = qv;
        }
    }

    f32x4 o[4];
    #pragma unroll
    for (int dt = 0; dt < 4; ++dt) o[dt] = (f32x4){0.f, 0.f, 0.f, 0.f};
    float mr = -1e30f, lr = 0.f;       // per-lane stats for q-row = m

    const int q  = qb + 16 * w + m;
    const int nt = qt + 1;

    const char* tb = KH;
    for (int jt = 0; jt < nt; ++jt, tb += PRE_TILE) {
        const bool last = (jt == nt - 1);
        const int  kvb  = jt * 64;

        // ---- K fragments -> regs (8 x dwordx4; L1-shared across waves) ----
        bf16x8 kf[8];
        #pragma unroll
        for (int i = 0; i < 8; ++i)
            kf[i] = *(const bf16x8*)(tb + i * 1024 + lane * 16);

        // ---- QK^T swapped: s[t] rows k=16t+4g+r, col q=m ----
        f32x4 s[4];
        #pragma unroll
        for (int t = 0; t < 4; ++t) s[t] = (f32x4){0.f, 0.f, 0.f, 0.f};
        #pragma unroll
        for (int c = 0; c < 2; ++c) {
            #pragma unroll
            for (int t = 0; t < 4; ++t)
                s[t] = __builtin_amdgcn_mfma_f32_16x16x32_bf16(kf[2*t+c], qf[c], s[t], 0, 0, 0);
        }

        // ---- V fragments -> regs; latency covered by softmax below ----
        bf16x8 vf[8];
        #pragma unroll
        for (int i = 0; i < 8; ++i)
            vf[i] = *(const bf16x8*)(tb + 8192 + i * 1024 + lane * 16);

        // ---- softmax: row q=m lane-local; 2 butterflies over g ----
        float mx = -1e30f;
        #pragma unroll
        for (int t = 0; t < 4; ++t) {
            #pragma unroll
            for (int r = 0; r < 4; ++r) {
                float v = s[t][r];
                if (last) {
                    const int kk = kvb + 16 * t + 4 * g + r;
                    v = (kk > q) ? -1e30f : v;
                }
                s[t][r] = v;
                mx = fmaxf(mx, v);
            }
        }
        mx = fmaxf(mx, __shfl_xor(mx, 16));
        mx = fmaxf(mx, __shfl_xor(mx, 32));

        if (__any(mx > mr)) {          // defer-rescale (THR=0, exact)
            const float mnew = fmaxf(mr, mx);
            const float fs   = exp2f(mr - mnew);
            mr = mnew;
            lr *= fs;
            float fso[4];
            #pragma unroll
            for (int r = 0; r < 4; ++r)
                fso[r] = __shfl(fs, (lane & 48) | (4 * g + r));
            #pragma unroll
            for (int dt = 0; dt < 4; ++dt) {
                #pragma unroll
                for (int r = 0; r < 4; ++r) o[dt][r] *= fso[r];
            }
        }

        float ps = 0.f;
        #pragma unroll
        for (int t = 0; t < 4; ++t) {
            const float p0 = exp2f(s[t][0] - mr);
            const float p1 = exp2f(s[t][1] - mr);
            const float p2 = exp2f(s[t][2] - mr);
            const float p3 = exp2f(s[t][3] - mr);
            ps += (p0 + p1) + (p2 + p3);
            uint2 e;
            e.x = pk2(p0, p1);
            e.y = pk2(p2, p3);
            const unsigned byte = (unsigned)(m * 128 + 32 * t + 8 * g);
            *(uint2*)(Pw + (byte ^ pswz)) = e;   // same-wave DS: in-order
        }
        ps += __shfl_xor(ps, 16);
        ps += __shfl_xor(ps, 32);
        lr += ps;

        // ---- PV from register V-fragments ----
        #pragma unroll
        for (int kc = 0; kc < 2; ++kc) {
            const unsigned ab = ((unsigned)(m * 128 + 64 * kc + 16 * g)) ^ pswz;
            bf16x8 pa = *(const bf16x8*)(Pw + ab);
            #pragma unroll
            for (int dt = 0; dt < 4; ++dt)
                o[dt] = __builtin_amdgcn_mfma_f32_16x16x32_bf16(pa, vf[kc*4+dt], o[dt], 0, 0, 0);
        }
    }

    // ---- epilogue ----
    const float invl = 1.0f / lr;
    float invo[4];
    #pragma unroll
    for (int r = 0; r < 4; ++r)
        invo[r] = __shfl(invl, (lane & 48) | (4 * g + r));
    #pragma unroll
    for (int r = 0; r < 4; ++r) {
        const int qrow = qb + 16 * w + 4 * g + r;
        float* dst = Op + (size_t)qrow * DH;
        #pragma unroll
        for (int dt = 0; dt < 4; ++dt) dst[16 * dt + m] = o[dt][r] * invo[r];
    }
}

// ---------------------------------------------------------------------------
// Fallback (validated round-4 kernel) if ws too small.
// ---------------------------------------------------------------------------
__global__ __launch_bounds__(256, 4) void fattn_s(const float* __restrict__ Qg,
                                                  const float* __restrict__ Kg,
                                                  const float* __restrict__ Vg,
                                                  float* __restrict__ Og)
{
    __shared__ __attribute__((aligned(16))) unsigned short Klds[128 * DH];
    __shared__ __attribute__((aligned(16))) unsigned short Vlds[DH * 128];
    __shared__ __attribute__((aligned(16))) unsigned short Plds[4][16 * 128];

    const int bid = blockIdx.x;
    const int hi4 = bid >> 8;
    const int lo8 = bid & 255;
    const int qx  = (int)((0x0F101F00u >> (8 * hi4)) & 31u);
    const int qt  = (lo8 & 31) ^ qx;
    const int bh  = (hi4 << 3) | (lo8 >> 5);
    const int qb  = qt * 64;

    const float* Qp = Qg + (size_t)bh * SLEN * DH;
    const float* Kp = Kg + (size_t)bh * SLEN * DH;
    const float* Vp = Vg + (size_t)bh * SLEN * DH;
    float*       Op = Og + (size_t)bh * SLEN * DH;

    const int tid  = threadIdx.x;
    const int w    = tid >> 6;
    const int lane = tid & 63;
    const int g    = lane >> 4;
    const int m    = lane & 15;

    bf16x8 qf[2];
    {
        const float sc = 0.125f * LOG2E;
        const int qrow = qb + 16 * w + m;
        #pragma unroll
        for (int c = 0; c < 2; ++c) {
            const float* src = Qp + (size_t)qrow * DH + 32 * c + 8 * g;
            float4 a = *reinterpret_cast<const float4*>(src);
            float4 b = *reinterpret_cast<const float4*>(src + 4);
            bf16x8 qv;
            qv[0]=(short)f2bf(a.x*sc); qv[1]=(short)f2bf(a.y*sc);
            qv[2]=(short)f2bf(a.z*sc); qv[3]=(short)f2bf(a.w*sc);
            qv[4]=(short)f2bf(b.x*sc); qv[5]=(short)f2bf(b.y*sc);
            qv[6]=(short)f2bf(b.z*sc); qv[7]=(short)f2bf(b.w*sc);
            qf[c] = qv;
        }
    }

    f32x4 o[4];
    #pragma unroll
    for (int dt = 0; dt < 4; ++dt) o[dt] = (f32x4){0.f, 0.f, 0.f, 0.f};
    float mrun = -1e30f, lrun = 0.f;

    const int klim = qb + 64;
    const int nt   = (qt + 2) >> 1;

    const int rk = tid & 127, hk = tid >> 7;
    const int kp = tid & 63,  dq = tid >> 6;

    char* Pw = (char*)&Plds[w][0];
    const unsigned pswz = ((unsigned)(m & 7)) << 4;
    const int q = qb + 16 * w + m;

    for (int jt = 0; jt < nt; ++jt) {
        const int kvb    = jt * 128;
        const int kwidth = min(128, klim - kvb);
        const bool last  = (jt == nt - 1);

        if (rk < kwidth) {
            const float4* s4 = reinterpret_cast<const float4*>(
                Kp + (size_t)(kvb + rk) * DH + 32 * hk);
            float4 x[8];
            #pragma unroll
            for (int i = 0; i < 8; ++i) x[i] = s4[i];
            const unsigned rswz = ((unsigned)(rk & 7)) << 4;
            #pragma unroll
            for (int c = 0; c < 4; ++c) {
                bf16x8 kb;
                kb[0]=(short)f2bf(x[2*c].x);   kb[1]=(short)f2bf(x[2*c].y);
                kb[2]=(short)f2bf(x[2*c].z);   kb[3]=(short)f2bf(x[2*c].w);
                kb[4]=(short)f2bf(x[2*c+1].x); kb[5]=(short)f2bf(x[2*c+1].y);
                kb[6]=(short)f2bf(x[2*c+1].z); kb[7]=(short)f2bf(x[2*c+1].w);
                const unsigned byte = (unsigned)(rk * 128 + 64 * hk + 16 * c);
                *(bf16x8*)((char*)Klds + (byte ^ rswz)) = kb;
            }
        }
        if (2 * kp < kwidth) {
            const float* s0 = Vp + (size_t)(kvb + 2 * kp) * DH + 16 * dq;
            float av[16], bv[16];
            #pragma unroll
            for (int i = 0; i < 4; ++i) {
                float4 ta = *reinterpret_cast<const float4*>(s0 + 4 * i);
                float4 tb = *reinterpret_cast<const float4*>(s0 + DH + 4 * i);
                av[4*i]=ta.x; av[4*i+1]=ta.y; av[4*i+2]=ta.z; av[4*i+3]=ta.w;
                bv[4*i]=tb.x; bv[4*i+1]=tb.y; bv[4*i+2]=tb.z; bv[4*i+3]=tb.w;
            }
            #pragma unroll
            for (int j = 0; j < 16; ++j) {
                const int d = 16 * dq + j;
                const unsigned byte = (unsigned)(d * 256 + 4 * kp);
                *(unsigned*)((char*)Vlds + (byte ^ (((unsigned)(d & 7)) << 4))) =
                    pk2(av[j], bv[j]);
            }
        }
        __syncthreads();

        f32x4 s[8];
        #pragma unroll
        for (int t = 0; t < 8; ++t) {
            if (16 * t < kwidth) {
                s[t] = (f32x4){0.f, 0.f, 0.f, 0.f};
                #pragma unroll
                for (int c = 0; c < 2; ++c) {
                    const unsigned row  = (unsigned)(16 * t + m);
                    const unsigned byte =
                        (row * 128u + (unsigned)(32 * c + 8 * g) * 2u) ^ ((row & 7u) << 4);
                    bf16x8 kf = *(const bf16x8*)((const char*)Klds + byte);
                    s[t] = __builtin_amdgcn_mfma_f32_16x16x32_bf16(kf, qf[c], s[t], 0, 0, 0);
                }
            }
        }

        float mx = -1e30f;
        #pragma unroll
        for (int t = 0; t < 8; ++t) {
            if (16 * t < kwidth) {
                #pragma unroll
                for (int r = 0; r < 4; ++r) {
                    float v = s[t][r];
                    if (last) {
                        const int kk = kvb + 16 * t + 4 * g + r;
                        v = (kk > q) ? -1e30f : v;
                    }
                    s[t][r] = v;
                    mx = fmaxf(mx, v);
                }
            }
        }
        mx = fmaxf(mx, __shfl_xor(mx, 16));
        mx = fmaxf(mx, __shfl_xor(mx, 32));
        const float mnew = fmaxf(mrun, mx);
        const float fs   = exp2f(mrun - mnew);
        mrun = mnew;

        float psum = 0.f;
        #pragma unroll
        for (int t = 0; t < 8; ++t) {
            if (16 * t < kwidth) {
                const float p0 = exp2f(s[t][0] - mnew);
                const float p1 = exp2f(s[t][1] - mnew);
                const float p2 = exp2f(s[t][2] - mnew);
                const float p3 = exp2f(s[t][3] - mnew);
                psum += (p0 + p1) + (p2 + p3);
                uint2 e;
                e.x = pk2(p0, p1);
                e.y = pk2(p2, p3);
                const unsigned byte = (unsigned)(m * 256 + 32 * t + 8 * g);
                *(uint2*)(Pw + (byte ^ pswz)) = e;
            }
        }
        psum += __shfl_xor(psum, 16);
        psum += __shfl_xor(psum, 32);
        lrun = lrun * fs + psum;

        float fso[4];
        #pragma unroll
        for (int r = 0; r < 4; ++r)
            fso[r] = __shfl(fs, (lane & 48) | (4 * g + r));
        #pragma unroll
        for (int dt = 0; dt < 4; ++dt) {
            #pragma unroll
            for (int r = 0; r < 4; ++r) o[dt][r] *= fso[r];
        }

        const int kclim = kwidth >> 5;
        #pragma unroll
        for (int kc = 0; kc < 4; ++kc) {
            if (kc < kclim) {
                const unsigned ab = ((unsigned)(m * 256 + 64 * kc + 16 * g)) ^ pswz;
                bf16x8 pa = *(const bf16x8*)(Pw + ab);
                #pragma unroll
                for (int dt = 0; dt < 4; ++dt) {
                    const unsigned d  = (unsigned)(16 * dt + m);
                    const unsigned vby =
                        (d * 256u + (unsigned)(64 * kc + 16 * g)) ^ ((d & 7u) << 4);
                    bf16x8 vfb = *(const bf16x8*)((const char*)Vlds + vby);
                    o[dt] = __builtin_amdgcn_mfma_f32_16x16x32_bf16(pa, vfb, o[dt], 0, 0, 0);
                }
            }
        }
        __syncthreads();
    }

    const float invl = 1.0f / lrun;
    float invo[4];
    #pragma unroll
    for (int r = 0; r < 4; ++r)
        invo[r] = __shfl(invl, (lane & 48) | (4 * g + r));
    #pragma unroll
    for (int r = 0; r < 4; ++r) {
        const int qrow = qb + 16 * w + 4 * g + r;
        float* dst = Op + (size_t)qrow * DH;
        #pragma unroll
        for (int dt = 0; dt < 4; ++dt) dst[16 * dt + m] = o[dt][r] * invo[r];
    }
}

extern "C" void kernel_launch(void* const* d_in, const int* in_sizes, int n_in,
                              void* d_out, int out_size, void* d_ws, size_t ws_size,
                              hipStream_t stream) {
    const float* Q = (const float*)d_in[0];
    const float* K = (const float*)d_in[1];
    const float* V = (const float*)d_in[2];
    float* O = (float*)d_out;
    if (ws_size >= PRE_TOTAL) {
        unsigned short* ws = (unsigned short*)d_ws;
        prep<<<dim3(3072), dim3(256), 0, stream>>>(K, V, ws);
        fattn_w<<<dim3(1024), dim3(256), 0, stream>>>(Q, ws, O);
    } else {
        fattn_s<<<dim3(1024), dim3(256), 0, stream>>>(Q, K, V, O);
    }
}